// Round 1
// baseline (839118.750 us; speedup 1.0000x reference)
//
#include <hip/hip_runtime.h>
#include <math.h>

#define T_STEPS 22550
#define NWG 32
#define NTHR 256

// ---- workspace layout (float offsets) ----
#define OF_H     64                      // h state [512]
#define OF_P1    (OF_H + 512)            // O1 partials [NWG][512]
#define OF_P3    (OF_P1 + NWG*512)       // O3 partials [NWG][512]
#define OF_AM1V  (OF_P3 + NWG*512)       // coarse argmax partial vals [NWG]
#define OF_AM1I  (OF_AM1V + NWG)         // coarse argmax partial idx  [NWG]
#define OF_AM2V  (OF_AM1I + NWG)
#define OF_AM2I  (OF_AM2V + NWG)
#define OF_O1WT  (OF_AM2I + NWG + 32)    // O1w^T [256][512]
#define OF_O3WT  (OF_O1WT + 256*512)     // O3w^T [256][512]
#define OF_BUFA  (OF_O3WT + 256*512)     // conv stage0 out [128][412]
#define OF_BUFB  (OF_BUFA + 128*412)     // conv stage1 out [128][2052]
#define OF_COND  (OF_BUFB + 128*2052)    // cond [T][128]
// total ~3.5M floats ~14MB

__global__ void k_init(float* ws){
  int i = threadIdx.x;
  if (i == 0) ((unsigned*)ws)[0] = 0u;   // barrier counter
  if (i < 512) ws[OF_H + i] = 0.f;       // h0 = 0
}

// transposed conv (lhs_dilation=sc), padding e, then relu.
// mode 0: y[c][j]; mode 1: write cond[t=j-1][c] (crop [1:-1], transpose)
__global__ void k_upconv(const float* __restrict__ x, int instride, int inoff,
                         const float* __restrict__ w, const float* __restrict__ b,
                         float* __restrict__ y, int Cin, int Lin, int K, int sc, int e,
                         int Lout, int mode)
{
  int j = blockIdx.x*blockDim.x + threadIdx.x;
  int c = blockIdx.y;
  if (j >= Lout) return;
  float acc = b[c];
  int kstart = ((e - j) % sc + sc) % sc;   // (j - e + k) % sc == 0
  for (int i = 0; i < Cin; ++i){
    const float* wci = w + (c*Cin + i)*K;
    const float* xi  = x + i*instride + inoff;
    for (int k = kstart; k < K; k += sc){
      int qd = j - e + k;
      if (qd >= 0){
        int qq = qd / sc;
        if (qq < Lin) acc += wci[k]*xi[qq];
      }
    }
  }
  acc = fmaxf(acc, 0.f);
  if (mode == 0) y[c*Lout + j] = acc;
  else { int t = j - 1; if (t >= 0 && t < T_STEPS) y[t*128 + c] = acc; }
}

__global__ void k_transpose(const float* __restrict__ src, float* __restrict__ dst,
                            int Rs, int Cs){
  // src[Rs][Cs] -> dst[Cs][Rs]
  int idx = blockIdx.x*blockDim.x + threadIdx.x;
  if (idx >= Rs*Cs) return;
  int e = idx / Rs, j = idx % Rs;
  dst[idx] = src[j*Cs + e];
}

// monotonic-counter global barrier (decoupled-lookback-style fences)
__device__ __forceinline__ void gbar(unsigned* ctr, unsigned target){
  __syncthreads();                 // compiler drains vmcnt before s_barrier
  if (threadIdx.x == 0){
    __threadfence();               // release our WG's global writes
    atomicAdd(ctr, 1u);
    while (__hip_atomic_load(ctr, __ATOMIC_RELAXED, __HIP_MEMORY_SCOPE_AGENT) < target) { }
  }
  __syncthreads();
  __threadfence();                 // acquire: invalidate caches before reading peers' data
}

__device__ __forceinline__ float sigm(float x){ return 1.f/(1.f + expf(-x)); }

__launch_bounds__(NTHR)
__global__ void k_wavernn(const float* __restrict__ Wx, const float* __restrict__ bx,
                          const float* __restrict__ Wh, const float* __restrict__ bh,
                          const float* __restrict__ O1b, const float* __restrict__ O2w,
                          const float* __restrict__ O2b, const float* __restrict__ O3b,
                          const float* __restrict__ O4w, const float* __restrict__ O4b,
                          float* ws, float* __restrict__ out)
{
  __shared__ __align__(16) float smem[1296];
  float* h_s  = smem;          // 512  current h
  float* m_s  = smem + 512;    // 128  cond[t]
  float* o_s  = smem + 640;    // 512  relu(O1/O3) activations
  float* hg_s = smem + 1152;   // 48   Wh@h + bh for owned rows
  float* xg1_s= smem + 1200;   // 48   xg (GRU1) for owned rows
  float* h1_s = smem + 1248;   // 16
  float* h2_s = smem + 1264;   // 16
  float* red_s= smem + 1280;   // 8    per-WG row maxima
  float* sc_s = smem + 1288;   // 8    [0]=c_val [1]=f_val [2]=c_cat [3]=c_new
  __shared__ float wc2_s[48];  // Wx[:,2] for owned rows

  const int tid = threadIdx.x, g = blockIdx.x;
  unsigned* ctr = (unsigned*)ws;
  float* h_glob = ws + OF_H;
  float* p1 = ws + OF_P1;  float* p3 = ws + OF_P3;
  float* am1v = ws + OF_AM1V; int* am1i = (int*)(ws + OF_AM1I);
  float* am2v = ws + OF_AM2V; int* am2i = (int*)(ws + OF_AM2I);
  const float* O1wT = ws + OF_O1WT;
  const float* O3wT = ws + OF_O3WT;
  const float* cond = ws + OF_COND;
  float* out_samp = out;
  float* out_log  = out + T_STEPS;

  // ownership: WG g owns h elements {g + 32*i, i=0..15}; rows {elem, 512+elem, 1024+elem}
  const int li   = tid >> 2;      // local row 0..47 (valid for tid<192)
  const int q    = tid & 3;       // K-quarter
  const int gate = li >> 4, ei = li & 15;
  const int elem = g + 32*ei;
  const int grow = gate*512 + elem;
  float bxv=0.f, bhv=0.f, wc0=0.f, wc1=0.f;
  if (tid < 192 && q == 0){
    bxv = bx[grow]; bhv = bh[grow];
    wc0 = Wx[grow*131+0]; wc1 = Wx[grow*131+1];
    wc2_s[li] = Wx[grow*131+2];
  }
  for (int k = tid; k < 512; k += NTHR) h_s[k] = 0.f;
  if (tid == 0){ sc_s[0] = 0.f; sc_s[1] = 0.f; }
  __syncthreads();

  for (int t = 0; t < T_STEPS; ++t){
    // refresh state (h_glob written by all owners before last barrier of prev step)
    if (tid < 128) m_s[tid] = cond[t*128 + tid];
    for (int k = tid; k < 512; k += NTHR) h_s[k] = h_glob[k];
    __syncthreads();
    const float c_val = sc_s[0], f_val = sc_s[1];

    // ---- P1: hg = Wh@h + bh ; xg1 = Wx[:,3:]@m + bx + c*w0 + f*w1 (4 lanes/row)
    if (tid < 192){
      const float4* WhR = (const float4*)(Wh + ((size_t)grow*512 + q*128));
      const float4* hR  = (const float4*)(h_s + q*128);
      float accH = 0.f;
      #pragma unroll 8
      for (int kk = 0; kk < 32; ++kk){
        float4 wv = WhR[kk], hv = hR[kk];
        accH += wv.x*hv.x + wv.y*hv.y + wv.z*hv.z + wv.w*hv.w;
      }
      const float* WxR = Wx + ((size_t)grow*131 + 3 + q*32);
      const float* mR  = m_s + q*32;
      float accX = 0.f;
      #pragma unroll 8
      for (int kk = 0; kk < 32; ++kk) accX += WxR[kk]*mR[kk];
      accH += __shfl_xor(accH, 1); accH += __shfl_xor(accH, 2);
      accX += __shfl_xor(accX, 1); accX += __shfl_xor(accX, 2);
      if (q == 0){
        hg_s[li]  = accH + bhv;
        xg1_s[li] = accX + bxv + c_val*wc0 + f_val*wc1;
      }
    }
    __syncthreads();
    // h1 for owned elements
    if (tid < 16){
      float r = sigm(xg1_s[tid]     + hg_s[tid]);
      float z = sigm(xg1_s[16+tid]  + hg_s[16+tid]);
      float n = tanhf(xg1_s[32+tid] + r*hg_s[32+tid]);
      h1_s[tid] = (1.f - z)*n + z*h_s[g + 32*tid];
    }
    __syncthreads();
    // partial O1: this WG's h1 columns (elements g+32i < 256 for i<8)
    for (int jj = tid; jj < 512; jj += NTHR){
      float p = 0.f;
      #pragma unroll
      for (int i = 0; i < 8; ++i) p += O1wT[(g + 32*i)*512 + jj]*h1_s[i];
      p1[g*512 + jj] = p;
    }
    gbar(ctr, (unsigned)(t*4 + 1)*NWG);

    // ---- P2: o1 = relu(sum partials + b); O2 rows {g+32m}
    for (int jj = tid; jj < 512; jj += NTHR){
      float a = O1b[jj];
      #pragma unroll 8
      for (int g2 = 0; g2 < NWG; ++g2) a += p1[g2*512 + jj];
      o_s[jj] = fmaxf(a, 0.f);
    }
    __syncthreads();
    {
      const int m = tid >> 5, l = tid & 31, row = g + 32*m;
      const float* wrow = O2w + (size_t)row*512;
      float acc = 0.f;
      #pragma unroll 4
      for (int k = l; k < 512; k += 32) acc += wrow[k]*o_s[k];
      acc += __shfl_xor(acc, 1); acc += __shfl_xor(acc, 2); acc += __shfl_xor(acc, 4);
      acc += __shfl_xor(acc, 8); acc += __shfl_xor(acc, 16);
      if (l == 0){ float v = acc + O2b[row]; out_log[(size_t)t*512 + row] = v; red_s[m] = v; }
    }
    __syncthreads();
    if (tid == 0){
      float bv = red_s[0]; int bi = g;             // rows ascend with m -> strict > == first max
      for (int m = 1; m < 8; ++m){ float v = red_s[m]; if (v > bv){ bv = v; bi = g + 32*m; } }
      am1v[g] = bv; am1i[g] = bi;
    }
    gbar(ctr, (unsigned)(t*4 + 2)*NWG);

    // ---- P3: global argmax (all WGs, deterministic), h2 update, partial O3
    if (tid == 0){
      float bv = -3.4e38f; int bi = 1<<30;
      for (int g2 = 0; g2 < NWG; ++g2){
        float v = am1v[g2]; int ix = am1i[g2];
        if (v > bv || (v == bv && ix < bi)){ bv = v; bi = ix; }
      }
      sc_s[2] = (float)bi;
      sc_s[3] = (float)bi/127.5f - 1.f;
    }
    __syncthreads();
    const float c_new = sc_s[3];
    if (tid < 16){
      float r = sigm(xg1_s[tid]     + c_new*wc2_s[tid]     + hg_s[tid]);
      float z = sigm(xg1_s[16+tid]  + c_new*wc2_s[16+tid]  + hg_s[16+tid]);
      float n = tanhf(xg1_s[32+tid] + c_new*wc2_s[32+tid]  + r*hg_s[32+tid]);
      int el = g + 32*tid;
      float h2 = (1.f - z)*n + z*h_s[el];
      h2_s[tid] = h2; h_s[el] = h2; h_glob[el] = h2;
    }
    __syncthreads();
    // partial O3: upper-half elements (i=8..15 -> columns g+32*(i-8))
    for (int jj = tid; jj < 512; jj += NTHR){
      float p = 0.f;
      #pragma unroll
      for (int i = 0; i < 8; ++i) p += O3wT[(g + 32*i)*512 + jj]*h2_s[8+i];
      p3[g*512 + jj] = p;
    }
    gbar(ctr, (unsigned)(t*4 + 3)*NWG);

    // ---- P4: o3 = relu(sum partials + b); O4 rows; fine argmax partials
    for (int jj = tid; jj < 512; jj += NTHR){
      float a = O3b[jj];
      #pragma unroll 8
      for (int g2 = 0; g2 < NWG; ++g2) a += p3[g2*512 + jj];
      o_s[jj] = fmaxf(a, 0.f);
    }
    __syncthreads();
    {
      const int m = tid >> 5, l = tid & 31, row = g + 32*m;
      const float* wrow = O4w + (size_t)row*512;
      float acc = 0.f;
      #pragma unroll 4
      for (int k = l; k < 512; k += 32) acc += wrow[k]*o_s[k];
      acc += __shfl_xor(acc, 1); acc += __shfl_xor(acc, 2); acc += __shfl_xor(acc, 4);
      acc += __shfl_xor(acc, 8); acc += __shfl_xor(acc, 16);
      if (l == 0){ float v = acc + O4b[row]; out_log[(size_t)t*512 + 256 + row] = v; red_s[m] = v; }
    }
    __syncthreads();
    if (tid == 0){
      float bv = red_s[0]; int bi = g;
      for (int m = 1; m < 8; ++m){ float v = red_s[m]; if (v > bv){ bv = v; bi = g + 32*m; } }
      am2v[g] = bv; am2i[g] = bi;
    }
    gbar(ctr, (unsigned)(t*4 + 4)*NWG);
    if (tid == 0){
      float bv = -3.4e38f; int bi = 1<<30;
      for (int g2 = 0; g2 < NWG; ++g2){
        float v = am2v[g2]; int ix = am2i[g2];
        if (v > bv || (v == bv && ix < bi)){ bv = v; bi = ix; }
      }
      sc_s[0] = sc_s[3];                       // c carry
      sc_s[1] = (float)bi/127.5f - 1.f;        // f carry
      if (g == 0) out_samp[t] = (sc_s[2]*256.f + (float)bi)/32767.5f - 1.f;
    }
    // loop-top __syncthreads() protects sc_s reads
  }
}

extern "C" void kernel_launch(void* const* d_in, const int* in_sizes, int n_in,
                              void* d_out, int out_size, void* d_ws, size_t ws_size,
                              hipStream_t stream)
{
  const float* mels  = (const float*)d_in[0];
  const float* up_w0 = (const float*)d_in[1]; const float* up_b0 = (const float*)d_in[2];
  const float* up_w1 = (const float*)d_in[3]; const float* up_b1 = (const float*)d_in[4];
  const float* up_w2 = (const float*)d_in[5]; const float* up_b2 = (const float*)d_in[6];
  const float* Wx  = (const float*)d_in[7];  const float* bx  = (const float*)d_in[8];
  const float* Wh  = (const float*)d_in[9];  const float* bh  = (const float*)d_in[10];
  const float* O1w = (const float*)d_in[11]; const float* O1b = (const float*)d_in[12];
  const float* O2w = (const float*)d_in[13]; const float* O2b = (const float*)d_in[14];
  const float* O3w = (const float*)d_in[15]; const float* O3b = (const float*)d_in[16];
  const float* O4w = (const float*)d_in[17]; const float* O4b = (const float*)d_in[18];
  float* ws  = (float*)d_ws;
  float* out = (float*)d_out;

  k_init<<<1, 512, 0, stream>>>(ws);

  // upsample: 84 -> 412 -> 2052 -> 22552 (crop [1:-1] -> cond[22550][128])
  k_upconv<<<dim3((412  +127)/128, 128), 128, 0, stream>>>(mels,        86,   1, up_w0, up_b0,
            ws+OF_BUFA,  80,   84, 11,  5, 3,   412, 0);
  k_upconv<<<dim3((2052 +127)/128, 128), 128, 0, stream>>>(ws+OF_BUFA, 412,   0, up_w1, up_b1,
            ws+OF_BUFB, 128,  412, 11,  5, 3,  2052, 0);
  k_upconv<<<dim3((22552+127)/128, 128), 128, 0, stream>>>(ws+OF_BUFB, 2052,  0, up_w2, up_b2,
            ws+OF_COND, 128, 2052, 23, 11, 6, 22552, 1);

  k_transpose<<<(256*512+255)/256, 256, 0, stream>>>(O1w, ws+OF_O1WT, 512, 256);
  k_transpose<<<(256*512+255)/256, 256, 0, stream>>>(O3w, ws+OF_O3WT, 512, 256);

  k_wavernn<<<NWG, NTHR, 0, stream>>>(Wx, bx, Wh, bh, O1b, O2w, O2b, O3b, O4w, O4b, ws, out);
}

// Round 2
// 454318.701 us; speedup vs baseline: 1.8470x; 1.8470x over previous
//
#include <hip/hip_runtime.h>
#include <math.h>

#define T_STEPS 22550
#define NWG 32
#define NTHR 256
#define SLOT 32              // floats per sync slot = 128B line

// ---- workspace layout (float offsets) ----
#define OF_FLAG1 64                      // uint flag per WG, 128B stride
#define OF_FLAG3 (OF_FLAG1 + NWG*SLOT)
#define OF_AM1   (OF_FLAG3 + NWG*SLOT)   // packed u64 (val|idx|tag) per WG, 128B stride
#define OF_AM2   (OF_AM1 + NWG*SLOT)
#define OF_HG    (OF_AM2 + NWG*SLOT)     // h2 exchange: elem (g + 32*i) stored at [g*SLOT + i]
#define OF_P1    (OF_HG + NWG*SLOT)      // O1 partials [NWG][512]
#define OF_P3    (OF_P1 + NWG*512)       // O3 partials [NWG][512]
#define OF_BUFA  (OF_P3 + NWG*512)       // conv stage0 out [128][412]
#define OF_BUFB  (OF_BUFA + 128*412)     // conv stage1 out [128][2052]
#define OF_COND  (OF_BUFB + 128*2052)    // cond [T][128]

__global__ void k_init(float* ws){
  int i = blockIdx.x*blockDim.x + threadIdx.x;
  if (i < 4*NWG*SLOT) ws[OF_FLAG1 + i] = 0.f;   // flags + packed argmax slots
}

// transposed conv (lhs_dilation=sc), padding e, then relu.
// mode 0: y[c][j]; mode 1: write cond[t=j-1][c] (crop [1:-1], transpose)
__global__ void k_upconv(const float* __restrict__ x, int instride, int inoff,
                         const float* __restrict__ w, const float* __restrict__ b,
                         float* __restrict__ y, int Cin, int Lin, int K, int sc, int e,
                         int Lout, int mode)
{
  int j = blockIdx.x*blockDim.x + threadIdx.x;
  int c = blockIdx.y;
  if (j >= Lout) return;
  float acc = b[c];
  int kstart = ((e - j) % sc + sc) % sc;   // (j - e + k) % sc == 0
  for (int i = 0; i < Cin; ++i){
    const float* wci = w + (c*Cin + i)*K;
    const float* xi  = x + i*instride + inoff;
    for (int k = kstart; k < K; k += sc){
      int qd = j - e + k;
      if (qd >= 0){
        int qq = qd / sc;
        if (qq < Lin) acc += wci[k]*xi[qq];
      }
    }
  }
  acc = fmaxf(acc, 0.f);
  if (mode == 0) y[c*Lout + j] = acc;
  else { int t = j - 1; if (t >= 0 && t < T_STEPS) y[t*128 + c] = acc; }
}

__device__ __forceinline__ float sigm(float x){ return 1.f/(1.f + expf(-x)); }

__device__ __forceinline__ void flag_store(unsigned* p, unsigned tag){
  __hip_atomic_store(p, tag, __ATOMIC_RELAXED, __HIP_MEMORY_SCOPE_AGENT);
}
__device__ __forceinline__ unsigned flag_load(unsigned* p){
  return __hip_atomic_load(p, __ATOMIC_RELAXED, __HIP_MEMORY_SCOPE_AGENT);
}

__launch_bounds__(NTHR)
__global__ void k_wavernn(const float* __restrict__ Wx, const float* __restrict__ bx,
                          const float* __restrict__ Wh, const float* __restrict__ bh,
                          const float* __restrict__ O1w, const float* __restrict__ O1b,
                          const float* __restrict__ O2w, const float* __restrict__ O2b,
                          const float* __restrict__ O3w, const float* __restrict__ O3b,
                          const float* __restrict__ O4w, const float* __restrict__ O4b,
                          float* ws, float* __restrict__ out)
{
  __shared__ __align__(16) float smem[1392];
  float* h_s  = smem;          // 512 current h
  float* m_s  = smem + 512;    // 128 cond row
  float* o_s  = smem + 640;    // 512 relu activations
  float* hg_s = smem + 1152;   // 48  Wh@h + bh (owned rows)
  float* xgb_s= smem + 1200;   // 48  Wx[:,3:]@m + bx (no c/f terms)
  float* xg1_s= smem + 1248;   // 48  xgb + c,f terms
  float* h1_s = smem + 1296;   // 16
  float* h2_s = smem + 1312;   // 16
  float* red_s= smem + 1328;   // 8   per-WG row maxima
  float* sc_s = smem + 1336;   // 8   [0]=c_val [1]=f_val [2]=c_cat [3]=c_new
  float* wc2_s= smem + 1344;   // 48  Wx[:,2] owned rows

  const int tid = threadIdx.x, g = blockIdx.x;
  unsigned* flag1 = (unsigned*)(ws + OF_FLAG1);
  unsigned* flag3 = (unsigned*)(ws + OF_FLAG3);
  unsigned long long* am1 = (unsigned long long*)(ws + OF_AM1);
  unsigned long long* am2 = (unsigned long long*)(ws + OF_AM2);
  float* hgl = ws + OF_HG;
  float* p1  = ws + OF_P1;
  float* p3  = ws + OF_P3;
  const float* cond = ws + OF_COND;
  float* out_samp = out;
  float* out_log  = out + T_STEPS;

  // gate-row ownership: WG g owns h elems {g+32i}; rows {e, 512+e, 1024+e}; 4 lanes/row
  const int li = tid >> 2, q = tid & 3;
  const int gate = li >> 4, ei = li & 15;
  const int elem = g + 32*ei;
  const int grow = gate*512 + elem;
  float bxv=0.f, bhv=0.f, wc0=0.f, wc1=0.f;
  if (tid < 192 && q == 0){
    bxv = bx[grow]; bhv = bh[grow];
    wc0 = Wx[(size_t)grow*131 + 0]; wc1 = Wx[(size_t)grow*131 + 1];
    wc2_s[li] = Wx[(size_t)grow*131 + 2];
  }

  // head-weight preload (registers, constant across steps)
  const int m8 = tid >> 5, l32 = tid & 31, row2 = g + 32*m8;
  float wO2r[16], wO4r[16];
  #pragma unroll
  for (int kk = 0; kk < 16; ++kk){
    wO2r[kk] = O2w[(size_t)row2*512 + l32 + 32*kk];
    wO4r[kk] = O4w[(size_t)row2*512 + l32 + 32*kk];
  }
  const float bO2 = O2b[row2], bO4 = O4b[row2];
  float wO1a[8], wO1b[8], wO3a[8], wO3b[8];
  #pragma unroll
  for (int i = 0; i < 8; ++i){
    int col = g + 32*i;
    wO1a[i] = O1w[(size_t)tid*256 + col];
    wO1b[i] = O1w[(size_t)(tid+256)*256 + col];
    wO3a[i] = O3w[(size_t)tid*256 + col];
    wO3b[i] = O3w[(size_t)(tid+256)*256 + col];
  }
  const float bo1a = O1b[tid], bo1b = O1b[tid+256];
  const float bo3a = O3b[tid], bo3b = O3b[tid+256];

  h_s[tid] = 0.f; h_s[tid+256] = 0.f;
  if (tid < 128) m_s[tid] = cond[tid];
  if (tid == 0){ sc_s[0] = 0.f; sc_s[1] = 0.f; }
  __syncthreads();

  // initial hg/xgb (h=0 -> hg=bh; xgb from m_0)
  #define COMPUTE_HX() do { \
    if (tid < 192){ \
      const float4* WhR = (const float4*)(Wh + ((size_t)grow*512 + q*128)); \
      const float4* hR  = (const float4*)(h_s + q*128); \
      float aH0 = 0.f, aH1 = 0.f; \
      _Pragma("unroll") \
      for (int kk = 0; kk < 32; kk += 2){ \
        float4 w0 = WhR[kk], v0 = hR[kk]; \
        float4 w1 = WhR[kk+1], v1 = hR[kk+1]; \
        aH0 += w0.x*v0.x + w0.y*v0.y + w0.z*v0.z + w0.w*v0.w; \
        aH1 += w1.x*v1.x + w1.y*v1.y + w1.z*v1.z + w1.w*v1.w; \
      } \
      float accH = aH0 + aH1; \
      const float* WxR = Wx + (size_t)grow*131 + 3 + q*32; \
      const float* mR  = m_s + q*32; \
      float accX = 0.f; \
      _Pragma("unroll") \
      for (int kk = 0; kk < 32; ++kk) accX += WxR[kk]*mR[kk]; \
      accH += __shfl_xor(accH, 1); accH += __shfl_xor(accH, 2); \
      accX += __shfl_xor(accX, 1); accX += __shfl_xor(accX, 2); \
      if (q == 0){ hg_s[li] = accH + bhv; xgb_s[li] = accX + bxv; } \
    } } while(0)

  COMPUTE_HX();

  for (int t = 0; t < T_STEPS; ++t){
    const unsigned tag = (unsigned)(t + 1);
    __syncthreads();                         // publish hg/xgb/sc from prev iter

    // ---- P1: xg1, h1 (elems < 256), O1 partial ----
    if (tid < 192 && q == 0) xg1_s[li] = xgb_s[li] + sc_s[0]*wc0 + sc_s[1]*wc1;
    __syncthreads();
    if (tid < 16){
      float r = sigm(xg1_s[tid]      + hg_s[tid]);
      float z = sigm(xg1_s[16+tid]   + hg_s[16+tid]);
      float n = tanhf(xg1_s[32+tid]  + r*hg_s[32+tid]);
      h1_s[tid] = (1.f - z)*n + z*h_s[g + 32*tid];
    }
    __syncthreads();
    {
      float a0 = 0.f, a1 = 0.f;
      #pragma unroll
      for (int i = 0; i < 8; ++i){ a0 += wO1a[i]*h1_s[i]; a1 += wO1b[i]*h1_s[i]; }
      p1[g*512 + tid] = a0; p1[g*512 + tid + 256] = a1;
    }
    __syncthreads();
    if (tid == 0){ __threadfence(); flag_store(&flag1[g*SLOT], tag); }
    if (tid < 32){ while (flag_load(&flag1[tid*SLOT]) != tag) __builtin_amdgcn_s_sleep(1); }
    __syncthreads();
    __threadfence();

    // ---- P2: o1 reduce, O2 rows, argmax exchange (fence-free packed slots) ----
    {
      float a0 = bo1a, a1 = bo1b;
      #pragma unroll 8
      for (int g2 = 0; g2 < NWG; ++g2){ a0 += p1[g2*512 + tid]; a1 += p1[g2*512 + tid + 256]; }
      o_s[tid] = fmaxf(a0, 0.f); o_s[tid+256] = fmaxf(a1, 0.f);
    }
    __syncthreads();
    {
      float acc = 0.f;
      #pragma unroll
      for (int kk = 0; kk < 16; ++kk) acc += wO2r[kk]*o_s[l32 + 32*kk];
      acc += __shfl_xor(acc, 1); acc += __shfl_xor(acc, 2); acc += __shfl_xor(acc, 4);
      acc += __shfl_xor(acc, 8); acc += __shfl_xor(acc, 16);
      if (l32 == 0){ float v = acc + bO2; out_log[(size_t)t*512 + row2] = v; red_s[m8] = v; }
    }
    __syncthreads();
    if (tid == 0){
      float bv = red_s[0]; int bi = g;          // rows ascend with m -> strict > = first max
      #pragma unroll
      for (int m = 1; m < 8; ++m){ float v = red_s[m]; if (v > bv){ bv = v; bi = g + 32*m; } }
      unsigned long long pk = ((unsigned long long)__float_as_uint(bv) << 32)
                            | ((unsigned long long)(unsigned)bi << 24) | tag;
      __hip_atomic_store(&am1[g*(SLOT/2)], pk, __ATOMIC_RELAXED, __HIP_MEMORY_SCOPE_AGENT);
    }
    if (tid < 32){
      unsigned long long pk;
      for (;;){
        pk = __hip_atomic_load(&am1[tid*(SLOT/2)], __ATOMIC_RELAXED, __HIP_MEMORY_SCOPE_AGENT);
        if ((unsigned)(pk & 0xFFFFFFu) == tag) break;
        __builtin_amdgcn_s_sleep(1);
      }
      float bv = __uint_as_float((unsigned)(pk >> 32));
      int   bi = (int)((pk >> 24) & 0xFFu);
      #pragma unroll
      for (int off = 16; off >= 1; off >>= 1){
        float ov = __shfl_xor(bv, off);
        int   oi = __shfl_xor(bi, off);
        if (ov > bv || (ov == bv && oi < bi)){ bv = ov; bi = oi; }
      }
      if (tid == 0){ sc_s[2] = (float)bi; sc_s[3] = (float)bi/127.5f - 1.f; }
    }
    __syncthreads();

    // ---- P3: h2 (reuse hg, xg1 + c_new*wc2), publish h2 + O3 partial ----
    if (tid < 16){
      float cn = sc_s[3];
      float r = sigm(xg1_s[tid]      + cn*wc2_s[tid]      + hg_s[tid]);
      float z = sigm(xg1_s[16+tid]   + cn*wc2_s[16+tid]   + hg_s[16+tid]);
      float n = tanhf(xg1_s[32+tid]  + cn*wc2_s[32+tid]   + r*hg_s[32+tid]);
      float h2 = (1.f - z)*n + z*h_s[g + 32*tid];
      h2_s[tid] = h2;
      hgl[g*SLOT + tid] = h2;                 // WG-exclusive 128B line
    }
    __syncthreads();
    {
      float a0 = 0.f, a1 = 0.f;
      #pragma unroll
      for (int i = 0; i < 8; ++i){ a0 += wO3a[i]*h2_s[8+i]; a1 += wO3b[i]*h2_s[8+i]; }
      p3[g*512 + tid] = a0; p3[g*512 + tid + 256] = a1;
    }
    __syncthreads();
    if (tid == 0){ __threadfence(); flag_store(&flag3[g*SLOT], tag); }
    if (tid < 32){ while (flag_load(&flag3[tid*SLOT]) != tag) __builtin_amdgcn_s_sleep(1); }
    __syncthreads();
    __threadfence();

    // ---- P4: gather h2, o3 reduce, O4 rows, publish f-partial, overlap hg(t+1), poll f ----
    h_s[tid]       = hgl[(tid & 31)*SLOT + (tid >> 5)];
    h_s[tid + 256] = hgl[(tid & 31)*SLOT + (tid >> 5) + 8];
    if (tid < 128 && t + 1 < T_STEPS) m_s[tid] = cond[(size_t)(t+1)*128 + tid];
    {
      float a0 = bo3a, a1 = bo3b;
      #pragma unroll 8
      for (int g2 = 0; g2 < NWG; ++g2){ a0 += p3[g2*512 + tid]; a1 += p3[g2*512 + tid + 256]; }
      o_s[tid] = fmaxf(a0, 0.f); o_s[tid+256] = fmaxf(a1, 0.f);
    }
    __syncthreads();
    {
      float acc = 0.f;
      #pragma unroll
      for (int kk = 0; kk < 16; ++kk) acc += wO4r[kk]*o_s[l32 + 32*kk];
      acc += __shfl_xor(acc, 1); acc += __shfl_xor(acc, 2); acc += __shfl_xor(acc, 4);
      acc += __shfl_xor(acc, 8); acc += __shfl_xor(acc, 16);
      if (l32 == 0){ float v = acc + bO4; out_log[(size_t)t*512 + 256 + row2] = v; red_s[m8] = v; }
    }
    __syncthreads();
    if (tid == 0){
      float bv = red_s[0]; int bi = g;
      #pragma unroll
      for (int m = 1; m < 8; ++m){ float v = red_s[m]; if (v > bv){ bv = v; bi = g + 32*m; } }
      unsigned long long pk = ((unsigned long long)__float_as_uint(bv) << 32)
                            | ((unsigned long long)(unsigned)bi << 24) | tag;
      __hip_atomic_store(&am2[g*(SLOT/2)], pk, __ATOMIC_RELAXED, __HIP_MEMORY_SCOPE_AGENT);
    }

    // overlap next step's big dots with f-argmax propagation
    COMPUTE_HX();

    if (tid < 32){
      unsigned long long pk;
      for (;;){
        pk = __hip_atomic_load(&am2[tid*(SLOT/2)], __ATOMIC_RELAXED, __HIP_MEMORY_SCOPE_AGENT);
        if ((unsigned)(pk & 0xFFFFFFu) == tag) break;
        __builtin_amdgcn_s_sleep(1);
      }
      float bv = __uint_as_float((unsigned)(pk >> 32));
      int   bi = (int)((pk >> 24) & 0xFFu);
      #pragma unroll
      for (int off = 16; off >= 1; off >>= 1){
        float ov = __shfl_xor(bv, off);
        int   oi = __shfl_xor(bi, off);
        if (ov > bv || (ov == bv && oi < bi)){ bv = ov; bi = oi; }
      }
      if (tid == 0){
        sc_s[0] = sc_s[3];                       // c carry
        sc_s[1] = (float)bi/127.5f - 1.f;        // f carry
        if (g == 0) out_samp[t] = (sc_s[2]*256.f + (float)bi)/32767.5f - 1.f;
      }
    }
    // loop-top __syncthreads() publishes hg/xgb/sc
  }
}

extern "C" void kernel_launch(void* const* d_in, const int* in_sizes, int n_in,
                              void* d_out, int out_size, void* d_ws, size_t ws_size,
                              hipStream_t stream)
{
  const float* mels  = (const float*)d_in[0];
  const float* up_w0 = (const float*)d_in[1]; const float* up_b0 = (const float*)d_in[2];
  const float* up_w1 = (const float*)d_in[3]; const float* up_b1 = (const float*)d_in[4];
  const float* up_w2 = (const float*)d_in[5]; const float* up_b2 = (const float*)d_in[6];
  const float* Wx  = (const float*)d_in[7];  const float* bx  = (const float*)d_in[8];
  const float* Wh  = (const float*)d_in[9];  const float* bh  = (const float*)d_in[10];
  const float* O1w = (const float*)d_in[11]; const float* O1b = (const float*)d_in[12];
  const float* O2w = (const float*)d_in[13]; const float* O2b = (const float*)d_in[14];
  const float* O3w = (const float*)d_in[15]; const float* O3b = (const float*)d_in[16];
  const float* O4w = (const float*)d_in[17]; const float* O4b = (const float*)d_in[18];
  float* ws  = (float*)d_ws;
  float* out = (float*)d_out;

  k_init<<<16, 256, 0, stream>>>(ws);

  // upsample: 84 -> 412 -> 2052 -> 22552 (crop [1:-1] -> cond[22550][128])
  k_upconv<<<dim3((412  +127)/128, 128), 128, 0, stream>>>(mels,        86,   1, up_w0, up_b0,
            ws+OF_BUFA,  80,   84, 11,  5, 3,   412, 0);
  k_upconv<<<dim3((2052 +127)/128, 128), 128, 0, stream>>>(ws+OF_BUFA, 412,   0, up_w1, up_b1,
            ws+OF_BUFB, 128,  412, 11,  5, 3,  2052, 0);
  k_upconv<<<dim3((22552+127)/128, 128), 128, 0, stream>>>(ws+OF_BUFB, 2052,  0, up_w2, up_b2,
            ws+OF_COND, 128, 2052, 23, 11, 6, 22552, 1);

  k_wavernn<<<NWG, NTHR, 0, stream>>>(Wx, bx, Wh, bh, O1w, O1b, O2w, O2b,
                                      O3w, O3b, O4w, O4b, ws, out);
}

// Round 3
// 339813.257 us; speedup vs baseline: 2.4694x; 1.3370x over previous
//
#include <hip/hip_runtime.h>
#include <math.h>

#define T_STEPS 22550
#define NWG 32
#define NTHR 256
#define SLOT 32              // floats per 128B line

// ---- workspace layout (float offsets) ----
#define OF_AM1   64                      // packed u64 argmax slots, 128B/WG
#define OF_AM2   (OF_AM1 + NWG*SLOT)
#define OF_H1E   (OF_AM2 + NWG*SLOT)     // 512 u64 tagged slots (owner-major g*16+i)
#define OF_O1E   (OF_H1E + 1024)         // 512 u64
#define OF_H2E   (OF_O1E + 1024)         // 512 u64
#define OF_O3E   (OF_H2E + 1024)         // 512 u64
#define OF_BUFA  (OF_O3E + 1024)         // conv stage0 out [128][412]
#define OF_BUFB  (OF_BUFA + 128*412)     // conv stage1 out [128][2052]
#define OF_COND  (OF_BUFB + 128*2052)    // cond [T][128]

__global__ void k_init(float* ws){
  int i = blockIdx.x*blockDim.x + threadIdx.x;   // 6144 slots total
  ws[OF_AM1 + i] = 0.f;
}

// transposed conv (lhs_dilation=sc), padding e, then relu.
// mode 0: y[c][j]; mode 1: write cond[t=j-1][c] (crop [1:-1], transpose)
__global__ void k_upconv(const float* __restrict__ x, int instride, int inoff,
                         const float* __restrict__ w, const float* __restrict__ b,
                         float* __restrict__ y, int Cin, int Lin, int K, int sc, int e,
                         int Lout, int mode)
{
  int j = blockIdx.x*blockDim.x + threadIdx.x;
  int c = blockIdx.y;
  if (j >= Lout) return;
  float acc = b[c];
  int kstart = ((e - j) % sc + sc) % sc;
  for (int i = 0; i < Cin; ++i){
    const float* wci = w + (c*Cin + i)*K;
    const float* xi  = x + i*instride + inoff;
    for (int k = kstart; k < K; k += sc){
      int qd = j - e + k;
      if (qd >= 0){
        int qq = qd / sc;
        if (qq < Lin) acc += wci[k]*xi[qq];
      }
    }
  }
  acc = fmaxf(acc, 0.f);
  if (mode == 0) y[c*Lout + j] = acc;
  else { int t = j - 1; if (t >= 0 && t < T_STEPS) y[t*128 + c] = acc; }
}

__device__ __forceinline__ float sigm(float x){ return 1.f/(1.f + expf(-x)); }

typedef unsigned long long ull;

__device__ __forceinline__ void slot_pub(ull* p, float v, unsigned tag){
  ull pk = ((ull)__float_as_uint(v) << 32) | (ull)tag;
  __hip_atomic_store(p, pk, __ATOMIC_RELAXED, __HIP_MEMORY_SCOPE_AGENT);
}
__device__ __forceinline__ float slot_get(ull* p, unsigned tag){
  ull pk;
  for (;;){
    pk = __hip_atomic_load(p, __ATOMIC_RELAXED, __HIP_MEMORY_SCOPE_AGENT);
    if ((unsigned)pk == tag) break;
    __builtin_amdgcn_s_sleep(1);
  }
  return __uint_as_float((unsigned)(pk >> 32));
}

__launch_bounds__(NTHR)
__global__ void k_wavernn(const float* __restrict__ Wx, const float* __restrict__ bx,
                          const float* __restrict__ Wh, const float* __restrict__ bh,
                          const float* __restrict__ O1w, const float* __restrict__ O1b,
                          const float* __restrict__ O2w, const float* __restrict__ O2b,
                          const float* __restrict__ O3w, const float* __restrict__ O3b,
                          const float* __restrict__ O4w, const float* __restrict__ O4b,
                          float* ws, float* __restrict__ out)
{
  __shared__ __align__(16) float smem[1616];
  float* h_s  = smem;          // 512 current h
  float* m_s  = smem + 512;    // 128 cond row
  float* o_s  = smem + 640;    // 512 relu activations (o1 or o3)
  float* h1c_s= smem + 1152;   // 256 gathered h1[:256]
  float* hg_s = smem + 1408;   // 48  Wh@h + bh (owned rows)
  float* xgb_s= smem + 1456;   // 48  Wx[:,3:]@m + bx
  float* xg1_s= smem + 1504;   // 48  xgb + c,f terms
  float* red_s= smem + 1552;   // 8   per-WG row maxima
  float* sc_s = smem + 1560;   // 8   [0]=c_val [1]=f_val [2]=c_cat [3]=c_new
  float* wc2_s= smem + 1568;   // 48  Wx[:,2] owned rows

  const int tid = threadIdx.x, g = blockIdx.x;
  ull* am1 = (ull*)(ws + OF_AM1);
  ull* am2 = (ull*)(ws + OF_AM2);
  ull* h1e = (ull*)(ws + OF_H1E);
  ull* o1e = (ull*)(ws + OF_O1E);
  ull* h2e = (ull*)(ws + OF_H2E);
  ull* o3e = (ull*)(ws + OF_O3E);
  const float* cond = ws + OF_COND;
  float* out_samp = out;
  float* out_log  = out + T_STEPS;

  // gate-row ownership: WG g owns h elems {g+32i}; rows {e, 512+e, 1024+e}; 4 lanes/row
  const int li = tid >> 2, q = tid & 3;
  const int gate = li >> 4, ei = li & 15;
  const int elem = g + 32*ei;
  const int grow = gate*512 + elem;
  float bxv=0.f, bhv=0.f, wc0=0.f, wc1=0.f;
  if (tid < 192 && q == 0){
    bxv = bx[grow]; bhv = bh[grow];
    wc0 = Wx[(size_t)grow*131 + 0]; wc1 = Wx[(size_t)grow*131 + 1];
    wc2_s[li] = Wx[(size_t)grow*131 + 2];
  }

  // head layer-2 (O2/O4): WG owns 8 logit rows {g+32m}, 32 lanes/row
  const int m8 = tid >> 5, l32 = tid & 31, row2 = g + 32*m8;
  float wO2r[16], wO4r[16];
  #pragma unroll
  for (int kk = 0; kk < 16; ++kk){
    wO2r[kk] = O2w[(size_t)row2*512 + l32 + 32*kk];
    wO4r[kk] = O4w[(size_t)row2*512 + l32 + 32*kk];
  }
  const float bO2 = O2b[row2], bO4 = O4b[row2];

  // head layer-1 (O1/O3): WG owns 16 o-rows {g+32m}, 16 lanes/row, 16 cols/lane
  const int m16 = tid >> 4, c16 = tid & 15, rowh = g + 32*m16;
  float wO1r[16], wO3r[16];
  #pragma unroll
  for (int kk = 0; kk < 16; ++kk){
    wO1r[kk] = O1w[(size_t)rowh*256 + c16*16 + kk];
    wO3r[kk] = O3w[(size_t)rowh*256 + c16*16 + kk];
  }
  const float bO1r = O1b[rowh], bO3r = O3b[rowh];

  h_s[tid] = 0.f; h_s[tid+256] = 0.f;
  if (tid < 128) m_s[tid] = cond[tid];
  if (tid == 0){ sc_s[0] = 0.f; sc_s[1] = 0.f; }
  __syncthreads();

  #define COMPUTE_HX() do { \
    if (tid < 192){ \
      const float4* WhR = (const float4*)(Wh + ((size_t)grow*512 + q*128)); \
      const float4* hR  = (const float4*)(h_s + q*128); \
      float aH0 = 0.f, aH1 = 0.f; \
      _Pragma("unroll") \
      for (int kk = 0; kk < 32; kk += 2){ \
        float4 w0 = WhR[kk], v0 = hR[kk]; \
        float4 w1 = WhR[kk+1], v1 = hR[kk+1]; \
        aH0 += w0.x*v0.x + w0.y*v0.y + w0.z*v0.z + w0.w*v0.w; \
        aH1 += w1.x*v1.x + w1.y*v1.y + w1.z*v1.z + w1.w*v1.w; \
      } \
      float accH = aH0 + aH1; \
      const float* WxR = Wx + (size_t)grow*131 + 3 + q*32; \
      const float* mR  = m_s + q*32; \
      float accX = 0.f; \
      _Pragma("unroll") \
      for (int kk = 0; kk < 32; ++kk) accX += WxR[kk]*mR[kk]; \
      accH += __shfl_xor(accH, 1); accH += __shfl_xor(accH, 2); \
      accX += __shfl_xor(accX, 1); accX += __shfl_xor(accX, 2); \
      if (q == 0){ hg_s[li] = accH + bhv; xgb_s[li] = accX + bxv; } \
    } } while(0)

  COMPUTE_HX();

  for (int t = 0; t < T_STEPS; ++t){
    const unsigned tag = (unsigned)(t + 1);
    __syncthreads();                       // publish hg/xgb/sc from prev iter

    // ---- GRU1 gates for owned elems < 256, publish h1 ----
    if (tid < 192 && q == 0) xg1_s[li] = xgb_s[li] + sc_s[0]*wc0 + sc_s[1]*wc1;
    __syncthreads();
    if (tid < 8){
      float r = sigm(xg1_s[tid]      + hg_s[tid]);
      float z = sigm(xg1_s[16+tid]   + hg_s[16+tid]);
      float n = tanhf(xg1_s[32+tid]  + r*hg_s[32+tid]);
      float h1 = (1.f - z)*n + z*h_s[g + 32*tid];
      slot_pub(&h1e[g*16 + tid], h1, tag);
    }
    // consume h1 (elem tid owned by WG tid&31, slot (tid&31)*16 + (tid>>5))
    h1c_s[tid] = slot_get(&h1e[(tid & 31)*16 + (tid >> 5)], tag);
    __syncthreads();

    // ---- O1: 16 rows/WG, publish relu'd o1 ----
    {
      const float4* hv = (const float4*)(h1c_s + c16*16);
      float acc = 0.f;
      #pragma unroll
      for (int kk = 0; kk < 4; ++kk){
        float4 h4 = hv[kk];
        acc += wO1r[4*kk]*h4.x + wO1r[4*kk+1]*h4.y + wO1r[4*kk+2]*h4.z + wO1r[4*kk+3]*h4.w;
      }
      acc += __shfl_xor(acc, 1); acc += __shfl_xor(acc, 2);
      acc += __shfl_xor(acc, 4); acc += __shfl_xor(acc, 8);
      if (c16 == 0) slot_pub(&o1e[g*16 + m16], fmaxf(acc + bO1r, 0.f), tag);
    }
    {
      int sl = (tid & 31)*16 + (tid >> 5);
      o_s[tid]       = slot_get(&o1e[sl], tag);
      o_s[tid + 256] = slot_get(&o1e[sl + 8], tag);
    }
    __syncthreads();

    // ---- O2 rows + coarse argmax exchange ----
    {
      float acc = 0.f;
      #pragma unroll
      for (int kk = 0; kk < 16; ++kk) acc += wO2r[kk]*o_s[l32 + 32*kk];
      acc += __shfl_xor(acc, 1); acc += __shfl_xor(acc, 2); acc += __shfl_xor(acc, 4);
      acc += __shfl_xor(acc, 8); acc += __shfl_xor(acc, 16);
      if (l32 == 0){ float v = acc + bO2; out_log[(size_t)t*512 + row2] = v; red_s[m8] = v; }
    }
    __syncthreads();
    if (tid == 0){
      float bv = red_s[0]; int bi = g;          // rows ascend with m -> strict > = first max
      #pragma unroll
      for (int m = 1; m < 8; ++m){ float v = red_s[m]; if (v > bv){ bv = v; bi = g + 32*m; } }
      ull pk = ((ull)__float_as_uint(bv) << 32) | ((ull)(unsigned)bi << 24) | tag;
      __hip_atomic_store(&am1[g*(SLOT/2)], pk, __ATOMIC_RELAXED, __HIP_MEMORY_SCOPE_AGENT);
    }
    if (tid < 32){
      ull pk;
      for (;;){
        pk = __hip_atomic_load(&am1[tid*(SLOT/2)], __ATOMIC_RELAXED, __HIP_MEMORY_SCOPE_AGENT);
        if ((unsigned)(pk & 0xFFFFFFu) == tag) break;
        __builtin_amdgcn_s_sleep(1);
      }
      float bv = __uint_as_float((unsigned)(pk >> 32));
      int   bi = (int)((pk >> 24) & 0xFFu);
      #pragma unroll
      for (int off = 16; off >= 1; off >>= 1){
        float ov = __shfl_xor(bv, off);
        int   oi = __shfl_xor(bi, off);
        if (ov > bv || (ov == bv && oi < bi)){ bv = ov; bi = oi; }
      }
      if (tid == 0){ sc_s[2] = (float)bi; sc_s[3] = (float)bi/127.5f - 1.f; }
    }
    __syncthreads();

    // ---- GRU2: h2 (reuse hg, xg1 + c_new*wc2), publish all 16 owned elems ----
    if (tid < 16){
      float cn = sc_s[3];
      float r = sigm(xg1_s[tid]      + cn*wc2_s[tid]      + hg_s[tid]);
      float z = sigm(xg1_s[16+tid]   + cn*wc2_s[16+tid]   + hg_s[16+tid]);
      float n = tanhf(xg1_s[32+tid]  + cn*wc2_s[32+tid]   + r*hg_s[32+tid]);
      float h2 = (1.f - z)*n + z*h_s[g + 32*tid];
      slot_pub(&h2e[g*16 + tid], h2, tag);
    }
    __syncthreads();                       // old-h reads done before h_s overwrite
    {
      int sl = (tid & 31)*16 + (tid >> 5);
      h_s[tid]       = slot_get(&h2e[sl], tag);
      h_s[tid + 256] = slot_get(&h2e[sl + 8], tag);
    }
    if (tid < 128 && t + 1 < T_STEPS) m_s[tid] = cond[(size_t)(t+1)*128 + tid];
    __syncthreads();

    // ---- O3: 16 rows/WG from h2 upper half, publish relu'd o3 ----
    {
      const float4* hv = (const float4*)(h_s + 256 + c16*16);
      float acc = 0.f;
      #pragma unroll
      for (int kk = 0; kk < 4; ++kk){
        float4 h4 = hv[kk];
        acc += wO3r[4*kk]*h4.x + wO3r[4*kk+1]*h4.y + wO3r[4*kk+2]*h4.z + wO3r[4*kk+3]*h4.w;
      }
      acc += __shfl_xor(acc, 1); acc += __shfl_xor(acc, 2);
      acc += __shfl_xor(acc, 4); acc += __shfl_xor(acc, 8);
      if (c16 == 0) slot_pub(&o3e[g*16 + m16], fmaxf(acc + bO3r, 0.f), tag);
    }
    {
      int sl = (tid & 31)*16 + (tid >> 5);
      o_s[tid]       = slot_get(&o3e[sl], tag);
      o_s[tid + 256] = slot_get(&o3e[sl + 8], tag);
    }
    __syncthreads();

    // ---- O4 rows + fine argmax (overlap next-step hg/xgb with the trip) ----
    {
      float acc = 0.f;
      #pragma unroll
      for (int kk = 0; kk < 16; ++kk) acc += wO4r[kk]*o_s[l32 + 32*kk];
      acc += __shfl_xor(acc, 1); acc += __shfl_xor(acc, 2); acc += __shfl_xor(acc, 4);
      acc += __shfl_xor(acc, 8); acc += __shfl_xor(acc, 16);
      if (l32 == 0){ float v = acc + bO4; out_log[(size_t)t*512 + 256 + row2] = v; red_s[m8] = v; }
    }
    __syncthreads();
    if (tid == 0){
      float bv = red_s[0]; int bi = g;
      #pragma unroll
      for (int m = 1; m < 8; ++m){ float v = red_s[m]; if (v > bv){ bv = v; bi = g + 32*m; } }
      ull pk = ((ull)__float_as_uint(bv) << 32) | ((ull)(unsigned)bi << 24) | tag;
      __hip_atomic_store(&am2[g*(SLOT/2)], pk, __ATOMIC_RELAXED, __HIP_MEMORY_SCOPE_AGENT);
    }

    COMPUTE_HX();                          // h_s = h2 already; m_s = cond[t+1]

    if (tid < 32){
      ull pk;
      for (;;){
        pk = __hip_atomic_load(&am2[tid*(SLOT/2)], __ATOMIC_RELAXED, __HIP_MEMORY_SCOPE_AGENT);
        if ((unsigned)(pk & 0xFFFFFFu) == tag) break;
        __builtin_amdgcn_s_sleep(1);
      }
      float bv = __uint_as_float((unsigned)(pk >> 32));
      int   bi = (int)((pk >> 24) & 0xFFu);
      #pragma unroll
      for (int off = 16; off >= 1; off >>= 1){
        float ov = __shfl_xor(bv, off);
        int   oi = __shfl_xor(bi, off);
        if (ov > bv || (ov == bv && oi < bi)){ bv = ov; bi = oi; }
      }
      if (tid == 0){
        sc_s[0] = sc_s[3];                       // c carry
        sc_s[1] = (float)bi/127.5f - 1.f;        // f carry
        if (g == 0) out_samp[t] = (sc_s[2]*256.f + (float)bi)/32767.5f - 1.f;
      }
    }
    // loop-top __syncthreads() publishes hg/xgb/sc
  }
}

extern "C" void kernel_launch(void* const* d_in, const int* in_sizes, int n_in,
                              void* d_out, int out_size, void* d_ws, size_t ws_size,
                              hipStream_t stream)
{
  const float* mels  = (const float*)d_in[0];
  const float* up_w0 = (const float*)d_in[1]; const float* up_b0 = (const float*)d_in[2];
  const float* up_w1 = (const float*)d_in[3]; const float* up_b1 = (const float*)d_in[4];
  const float* up_w2 = (const float*)d_in[5]; const float* up_b2 = (const float*)d_in[6];
  const float* Wx  = (const float*)d_in[7];  const float* bx  = (const float*)d_in[8];
  const float* Wh  = (const float*)d_in[9];  const float* bh  = (const float*)d_in[10];
  const float* O1w = (const float*)d_in[11]; const float* O1b = (const float*)d_in[12];
  const float* O2w = (const float*)d_in[13]; const float* O2b = (const float*)d_in[14];
  const float* O3w = (const float*)d_in[15]; const float* O3b = (const float*)d_in[16];
  const float* O4w = (const float*)d_in[17]; const float* O4b = (const float*)d_in[18];
  float* ws  = (float*)d_ws;
  float* out = (float*)d_out;

  k_init<<<24, 256, 0, stream>>>(ws);      // zero all 6144 slot floats

  // upsample: 84 -> 412 -> 2052 -> 22552 (crop [1:-1] -> cond[22550][128])
  k_upconv<<<dim3((412  +127)/128, 128), 128, 0, stream>>>(mels,        86,   1, up_w0, up_b0,
            ws+OF_BUFA,  80,   84, 11,  5, 3,   412, 0);
  k_upconv<<<dim3((2052 +127)/128, 128), 128, 0, stream>>>(ws+OF_BUFA, 412,   0, up_w1, up_b1,
            ws+OF_BUFB, 128,  412, 11,  5, 3,  2052, 0);
  k_upconv<<<dim3((22552+127)/128, 128), 128, 0, stream>>>(ws+OF_BUFB, 2052,  0, up_w2, up_b2,
            ws+OF_COND, 128, 2052, 23, 11, 6, 22552, 1);

  k_wavernn<<<NWG, NTHR, 0, stream>>>(Wx, bx, Wh, bh, O1w, O1b, O2w, O2b,
                                      O3w, O3b, O4w, O4b, ws, out);
}